// Round 5
// baseline (245.143 us; speedup 1.0000x reference)
//
#include <hip/hip_runtime.h>

#define D 4096

// In-register 64-point Walsh-Hadamard over the register-index bits, processing
// butterfly bits in INCREASING order (s=1..32) — matches the reference's stage
// order so the whole kernel's op DAG is bitwise-identical to the jax reference.
__device__ __forceinline__ void fwht64(float v[64]) {
#pragma unroll
    for (int s = 1; s < 64; s <<= 1) {
#pragma unroll
        for (int i = 0; i < 64; i++) {
            if (!(i & s)) {
                float a = v[i], b = v[i ^ s];
                v[i]     = a + b;
                v[i ^ s] = a - b;
            }
        }
    }
}

// One WAVE per row: 64 threads x 64 floats = 4096 elements, zero barriers.
//   Phase 1: thread l holds elements e = 64l + r (r = reg index = e[5:0]).
//            Load = 16 dwordx4/lane (256 B contiguous per lane); H64 over bits 0-5.
//   Transpose: XOR-swizzled 64x64 through LDS, f(e) = 64*(e&63) + ((e>>6)^(e&63)).
//            Write instr r:  lanes hit f = 64r + (l^r)  -> permutation of one row,
//            banks (l^r)&31 = 2-way (free). Read instr r: f = 64l + (l^r), banks
//            (l^r)&31 = 2-way (free). Zero padding -> LDS = exactly 16 KB ->
//            10 blocks/CU resident.
//   Phase 2: thread l holds e = 64r + l; H64 over bits 6-11; store instr r writes
//            64 consecutive floats (256 B contiguous, streaming).
// Single-wave blocks need no __syncthreads(): a wave's DS ops execute in order;
// one lgkmcnt fence separates transpose write/read. No barrier ever drains vmcnt,
// so 10 independent rows/CU keep a continuous load+store stream at the memory
// controller (the round-0/2 structure convoyed on 2 barriers/row and stuck at
// ~70 us with every pipe <35%).
__global__ __launch_bounds__(64) void fwht_kernel(const float* __restrict__ x,
                                                  const float* __restrict__ signs,
                                                  float* __restrict__ out) {
    __shared__ float lds[4096];  // exactly 16 KB

    const int l = threadIdx.x;   // 0..63
    const long row = blockIdx.x;

    float v[64];

    // ---- P1 load: v[r] = x[row*D + 64l + r] * signs[64l + r] ----
    {
        const float4* __restrict__ xv = (const float4*)(x + row * (long)D + l * 64);
        const float4* __restrict__ sv = (const float4*)(signs + l * 64);
#pragma unroll
        for (int k = 0; k < 16; k++) {
            float4 a = xv[k];
            float4 s = sv[k];
            v[4 * k + 0] = a.x * s.x;
            v[4 * k + 1] = a.y * s.y;
            v[4 * k + 2] = a.z * s.z;
            v[4 * k + 3] = a.w * s.w;
        }
    }
    fwht64(v);  // butterfly bits 0..5 (reference order)

    // ---- XOR-swizzled transpose (both sides bank-conflict-free) ----
#pragma unroll
    for (int r = 0; r < 64; r++) lds[64 * r + (l ^ r)] = v[r];
    // Same-wave DS ordering makes this safe; the fence orders the reads after
    // all writes, and sched_barrier pins the fence (guide rule #18).
    asm volatile("s_waitcnt lgkmcnt(0)" ::: "memory");
    __builtin_amdgcn_sched_barrier(0);
#pragma unroll
    for (int r = 0; r < 64; r++) v[r] = lds[64 * l + (l ^ r)];

    fwht64(v);  // butterfly bits 6..11 (reference order)

    // ---- store: out[row*D + 64r + l], 256 B contiguous per instruction ----
    const float scale = 1.0f / 64.0f;  // 4096^-0.5
    float* __restrict__ orow = out + row * (long)D + l;
#pragma unroll
    for (int r = 0; r < 64; r++) orow[64 * r] = v[r] * scale;
}

extern "C" void kernel_launch(void* const* d_in, const int* in_sizes, int n_in,
                              void* d_out, int out_size, void* d_ws, size_t ws_size,
                              hipStream_t stream) {
    const float* x = (const float*)d_in[0];
    const float* signs = (const float*)d_in[1];
    float* out = (float*)d_out;
    const int rows = in_sizes[0] / D;  // 8192
    fwht_kernel<<<dim3(rows), dim3(64), 0, stream>>>(x, signs, out);
}